// Round 9
// baseline (501.259 us; speedup 1.0000x reference)
//
#include <hip/hip_runtime.h>
#include <hip/hip_bf16.h>
#include <math.h>

#define N_LOC   8192
#define C_SIZE  2048
#define A_SIZE  512
#define CTRL_IN 1024
#define D_FULL  2560   // A_SIZE + C_SIZE
#define EPS_F   1e-7f
#define NCHUNK  256    // row chunks for read_vec partials (8192/NCHUNK=32 rows/chunk)
#define NBLK_K1 8704

typedef float f4 __attribute__((ext_vector_type(4)));

__device__ __forceinline__ f4 nt4(const f4* p) { return __builtin_nontemporal_load(p); }
__device__ __forceinline__ float hsum4(f4 v) { return v.x + v.y + v.z + v.w; }

__device__ __forceinline__ float waveReduceSum(float v) {
    #pragma unroll
    for (int off = 32; off > 0; off >>= 1) v += __shfl_xor(v, off, 64);
    return v;
}
__device__ __forceinline__ float waveReduceMax(float v) {
    #pragma unroll
    for (int off = 32; off > 0; off >>= 1) v = fmaxf(v, __shfl_xor(v, off, 64));
    return v;
}

// ---------------------------------------------------------------- K1: all mat-vecs + fused scalars
// CACHING POLICY (R5-R8 A/B measured): nt ONLY on single-use weight streams.
//  - nt W loads: matvec 82 -> <49 us (R6).
//  - ma/mc MUST stay cached: nt reads cost +16 us (R8) - L3 reuse K3->K5 is real.
//  - nt newmem store: -2.3 us (R6 vs R8) + keeps L3 for ma/mc.
// Last block (atomic counter) computes the K2 scalars + cdiff inline, saving a
// serialized dispatch. Counter memset to 0 every launch (graph-safe).
__global__ __launch_bounds__(256) void k_matvec(
    const float* __restrict__ h, const float* __restrict__ x,
    const float* __restrict__ Wq, const float* __restrict__ bq,
    const float* __restrict__ We, const float* __restrict__ be,
    const float* __restrict__ Wch, const float* __restrict__ Wci,
    const float* __restrict__ us, const float* __restrict__ bs,
    const float* __restrict__ ul, const float* __restrict__ bl,
    const float* __restrict__ uca, const float* __restrict__ bca,
    float* __restrict__ q_out, float* __restrict__ erase_out,
    float* __restrict__ wh_out, float* __restrict__ wx_out,
    float* __restrict__ scal, float* __restrict__ cdiff,
    int* __restrict__ counter)
{
    __shared__ float red[4];
    __shared__ int s_last;
    int tid  = threadIdx.x;
    int lane = tid & 63;
    int wid  = tid >> 6;
    int blk  = blockIdx.x;

    float acc;
    float bias = 0.f;
    float* out;

    if (blk < 6656) {
        const float* W;
        if (blk < 2560)      { int r = blk;        W = Wq  + (size_t)r * 8192; bias = bq[r]; out = q_out + r; }
        else if (blk < 4608) { int r = blk - 2560; W = We  + (size_t)r * 8192; bias = be[r]; out = erase_out + r; }
        else                 { int r = blk - 4608; W = Wch + (size_t)r * 8192; out = wh_out + r; }

        const f4* W4 = (const f4*)W;
        const f4* h4 = (const f4*)h;
        f4 w[8], v[8];
        #pragma unroll
        for (int u = 0; u < 8; ++u) w[u] = nt4(W4 + tid + 256 * u);
        #pragma unroll
        for (int u = 0; u < 8; ++u) v[u] = h4[tid + 256 * u];
        f4 a4 = w[0] * v[0];
        #pragma unroll
        for (int u = 1; u < 8; ++u) a4 += w[u] * v[u];
        acc = hsum4(a4);
    } else {
        int r = blk - 6656;              // 0..2047
        const f4* W4 = (const f4*)(Wci + (size_t)r * 1024);
        const f4* x4 = (const f4*)x;
        f4 w = nt4(W4 + tid);
        f4 v = x4[tid];
        acc = hsum4(w * v);
        out = wx_out + r;
    }

    acc = waveReduceSum(acc);
    if (lane == 0) red[wid] = acc;
    __syncthreads();
    if (tid == 0) {
        *out = red[0] + red[1] + red[2] + red[3] + bias;
        __threadfence();                       // release: output visible device-wide
        int old = atomicAdd(counter, 1);
        s_last = (old == NBLK_K1 - 1) ? 1 : 0;
    }
    __syncthreads();
    if (!s_last) return;

    // ---- fused K2 (runs in exactly one block, after all outputs are visible)
    __threadfence();                           // acquire
    __shared__ float red2[16];
    __shared__ float sh_alpha;
    const f4* h4   = (const f4*)h;
    const f4* us4  = (const f4*)us;
    const f4* ul4  = (const f4*)ul;
    const f4* uca4 = (const f4*)uca;
    const f4* x4   = (const f4*)x;
    const f4* q4   = (const f4*)q_out;
    const f4* e4   = (const f4*)erase_out;
    const f4* wh4  = (const f4*)wh_out;
    const f4* wx4  = (const f4*)wx_out;

    f4 aus = {0.f,0.f,0.f,0.f}, aul = aus, aa = aus, aq = aus;
    for (int i = tid; i < 2048; i += 256) {
        f4 hv = h4[i];
        aus += us4[i] * hv;
        aul += ul4[i] * hv;
        aa  += uca4[i] * hv;
    }
    { f4 xv = x4[tid]; aa += uca4[2048 + tid] * xv; }   // x: 256 f4, tid covers all
    for (int i = tid; i < 640; i += 256) { f4 qv = q4[i]; aq += qv * qv; }

    float vals[4] = { hsum4(aus), hsum4(aul), hsum4(aa), hsum4(aq) };
    float res[4];
    #pragma unroll
    for (int k = 0; k < 4; ++k) {
        float v = waveReduceSum(vals[k]);
        __syncthreads();
        if (lane == 0) red2[wid] = v;
        __syncthreads();
        float r = 0.f;
        if (tid == 0) { for (int i = 0; i < 4; ++i) r += red2[i]; }
        res[k] = r;
    }

    if (tid == 0) {
        float z = res[0] + bs[0];
        float sp = (z > 20.f) ? z : log1pf(expf(z));
        float beta  = sp + 1.0f;
        float gamma = 1.f / (1.f + expf(-(res[1] + bl[0])));
        float alpha = res[2] + bca[0];
        float qn    = fmaxf(sqrtf(res[3]), EPS_F);
        scal[0] = beta; scal[1] = gamma; scal[2] = qn; scal[3] = alpha;
        sh_alpha = alpha;
    }
    __syncthreads();
    float al = sh_alpha;
    for (int j = tid; j < 512; j += 256) {
        f4 whv = wh4[j], wxv = wx4[j], ev = e4[j];
        f4 r;
        r.x = fmaxf(whv.x + al * wxv.x, 0.f) - ev.x;
        r.y = fmaxf(whv.y + al * wxv.y, 0.f) - ev.y;
        r.z = fmaxf(whv.z + al * wxv.z, 0.f) - ev.z;
        r.w = fmaxf(whv.w + al * wxv.w, 0.f) - ev.w;
        ((f4*)cdiff)[j] = r;
    }
}

// ---------------------------------------------------------------- K3: row pass (dots, norms, logits, new_ema)
// Cached reads: allocates ma/mc into L3 so K5 hits (R8 proved this reuse is worth 16us).
__global__ void k_rowpass(const float* __restrict__ ma, const float* __restrict__ mc,
                          const float* __restrict__ q, const float* __restrict__ ema,
                          const float* __restrict__ scal,
                          float* __restrict__ logit, float* __restrict__ newema_out)
{
    int wave = (blockIdx.x * blockDim.x + threadIdx.x) >> 6;
    int lane = threadIdx.x & 63;
    if (wave >= N_LOC) return;
    int row = wave;

    const f4* a4 = (const f4*)(ma + (size_t)row * A_SIZE);
    const f4* c4 = (const f4*)(mc + (size_t)row * C_SIZE);
    const f4* q4 = (const f4*)q;

    f4 dv = {0.f, 0.f, 0.f, 0.f}, sv = {0.f, 0.f, 0.f, 0.f};
    #pragma unroll
    for (int i = lane; i < 128; i += 64) {           // address part: 512 floats
        f4 v = a4[i], qq = q4[i];
        dv += v * qq;
        sv += v * v;
    }
    #pragma unroll
    for (int i = lane; i < 512; i += 64) {           // contents part: 2048 floats
        f4 v = c4[i], qq = q4[128 + i];
        dv += v * qq;
        sv += v * v;
    }
    float dot = hsum4(dv);
    float ssq = hsum4(sv);
    dot = waveReduceSum(dot);
    ssq = waveReduceSum(ssq);
    if (lane == 0) {
        float beta = scal[0], gamma = scal[1], qn = scal[2];
        float mn  = fmaxf(sqrtf(ssq), EPS_F);
        float sim = beta * dot / (mn * qn);
        float e   = ema[row];
        logit[row]      = sim - gamma * e;
        newema_out[row] = 0.1f * e + 0.9f * sim;
    }
}

// ---------------------------------------------------------------- K4: softmax over 8192 logits
__global__ void k_softmax(const float* __restrict__ logit, float* __restrict__ addr_out)
{
    __shared__ float red[16];
    __shared__ float s_max, s_sum;
    int tid = threadIdx.x, lane = tid & 63, wid = tid >> 6;

    float v[8];
    float lmax = -INFINITY;
    #pragma unroll
    for (int k = 0; k < 8; ++k) { v[k] = logit[tid + k * 1024]; lmax = fmaxf(lmax, v[k]); }
    lmax = waveReduceMax(lmax);
    if (lane == 0) red[wid] = lmax;
    __syncthreads();
    if (tid == 0) { float m = red[0]; for (int i = 1; i < 16; ++i) m = fmaxf(m, red[i]); s_max = m; }
    __syncthreads();
    float m = s_max, lsum = 0.f;
    #pragma unroll
    for (int k = 0; k < 8; ++k) { v[k] = expf(v[k] - m); lsum += v[k]; }
    lsum = waveReduceSum(lsum);
    __syncthreads();
    if (lane == 0) red[wid] = lsum;
    __syncthreads();
    if (tid == 0) { float s = 0.f; for (int i = 0; i < 16; ++i) s += red[i]; s_sum = s; }
    __syncthreads();
    float inv = 1.f / s_sum;
    #pragma unroll
    for (int k = 0; k < 8; ++k) addr_out[tid + k * 1024] = v[k] * inv;
}

// ---------------------------------------------------------------- K5: fused column pass (new_mem + read_vec partials)
// float4 per thread (16B/lane, G13), cached ma/mc reads (L3 hits from K3),
// nt stores for newmem (single write; keeps L3 for ma/mc).
// grid (2, NCHUNK), block 320: thread owns one f4-column within a 32-row chunk.
__global__ __launch_bounds__(320) void k_colpass(
    const float* __restrict__ ma, const float* __restrict__ mc,
    const float* __restrict__ addr, const float* __restrict__ cdiff,
    float* __restrict__ newmem_out, float* __restrict__ rvpart)
{
    int c4    = blockIdx.x * 320 + threadIdx.x;   // 0..639 (f4 column)
    int chunk = blockIdx.y;                       // 0..NCHUNK-1
    const int RPC = N_LOC / NCHUNK;               // 32
    int r0 = chunk * RPC, r1 = r0 + RPC;

    f4 acc = {0.f, 0.f, 0.f, 0.f};
    if (c4 < 128) {                               // ma region: 128 f4 per row
        const f4* p = (const f4*)ma + c4;
        for (int r = r0; r < r1; ++r) {
            f4 v = p[(size_t)r * 128];
            float a = addr[r];
            if (r != N_LOC - 1) acc += a * v;
        }
    } else {                                      // mc region: 512 f4 per row
        int cc = c4 - 128;
        f4 cd = ((const f4*)cdiff)[cc];
        const f4* p = (const f4*)mc + cc;
        f4* o = (f4*)newmem_out + cc;
        for (int r = r0; r < r1; ++r) {
            f4 v = p[(size_t)r * 512];
            float a = addr[r];
            if (r != N_LOC - 1) acc += a * v;
            __builtin_nontemporal_store(v + a * cd, o + (size_t)r * 512);
        }
    }
    ((f4*)rvpart)[(size_t)chunk * 640 + c4] = acc;
}

// ---------------------------------------------------------------- K6: reduce read_vec partials (f4)
__global__ void k_rvreduce(const float* __restrict__ rvpart, float* __restrict__ rv_out)
{
    int c4 = blockIdx.x * 256 + threadIdx.x;
    if (c4 >= 640) return;
    const f4* rp = (const f4*)rvpart;
    f4 s = {0.f, 0.f, 0.f, 0.f};
    for (int k = 0; k < NCHUNK; ++k) s += rp[(size_t)k * 640 + c4];
    ((f4*)rv_out)[c4] = s;
}

// ---------------------------------------------------------------- launch
extern "C" void kernel_launch(void* const* d_in, const int* in_sizes, int n_in,
                              void* d_out, int out_size, void* d_ws, size_t ws_size,
                              hipStream_t stream)
{
    const float* h   = (const float*)d_in[0];
    const float* x   = (const float*)d_in[1];
    const float* mc  = (const float*)d_in[2];
    const float* ma  = (const float*)d_in[3];
    const float* ema = (const float*)d_in[4];
    const float* Wq  = (const float*)d_in[5];
    const float* bq  = (const float*)d_in[6];
    const float* us  = (const float*)d_in[7];
    const float* bs  = (const float*)d_in[8];
    const float* ul  = (const float*)d_in[9];
    const float* bl  = (const float*)d_in[10];
    const float* We  = (const float*)d_in[11];
    const float* be  = (const float*)d_in[12];
    const float* Wch = (const float*)d_in[13];
    const float* Wci = (const float*)d_in[14];
    const float* uca = (const float*)d_in[15];
    const float* bca = (const float*)d_in[16];

    float* out = (float*)d_out;
    float* rv_out     = out;                              // 2560
    float* newmem_out = out + D_FULL;                     // 8192*2048
    float* addr_out   = newmem_out + (size_t)N_LOC * C_SIZE; // 8192
    float* newema_out = addr_out + N_LOC;                 // 8192

    float* ws = (float*)d_ws;
    float* w_query   = ws;            // 2560
    float* w_erase   = ws + 2560;     // 2048
    float* w_wh      = ws + 4608;     // 2048
    float* w_wx      = ws + 6656;     // 2048
    float* w_cdiff   = ws + 8704;     // 2048
    float* w_scal    = ws + 10752;    // 4
    int*   w_counter = (int*)(ws + 10756);
    float* w_logit   = ws + 10760;    // 8192
    float* w_rvp     = ws + 18952;    // NCHUNK*2560

    // reset the last-block counter every call (graph-capturable memset node)
    hipMemsetAsync(w_counter, 0, sizeof(int), stream);

    // K1: all mat-vecs + fused scalars/cdiff (6656 h-rows + 2048 x-rows)
    k_matvec<<<NBLK_K1, 256, 0, stream>>>(h, x, Wq, bq, We, be, Wch, Wci,
                                          us, bs, ul, bl, uca, bca,
                                          w_query, w_erase, w_wh, w_wx,
                                          w_scal, w_cdiff, w_counter);
    // K3: per-row dot/norm -> logit, new_ema (cached: allocates ma/mc for K5)
    k_rowpass<<<2048, 256, 0, stream>>>(ma, mc, w_query, ema, w_scal, w_logit, newema_out);
    // K4: softmax -> address
    k_softmax<<<1, 1024, 0, stream>>>(w_logit, addr_out);
    // K5: fused new_mem + read_vec partials (f4, cached reads, nt stores)
    dim3 g5(2, NCHUNK);
    k_colpass<<<g5, 320, 0, stream>>>(ma, mc, addr_out, w_cdiff, newmem_out, w_rvp);
    // K6: reduce read_vec partials
    k_rvreduce<<<3, 256, 0, stream>>>(w_rvp, rv_out);
}

// Round 10
// 103.116 us; speedup vs baseline: 4.8611x; 4.8611x over previous
//
#include <hip/hip_runtime.h>
#include <hip/hip_bf16.h>
#include <math.h>

#define N_LOC   8192
#define C_SIZE  2048
#define A_SIZE  512
#define CTRL_IN 1024
#define D_FULL  2560   // A_SIZE + C_SIZE
#define EPS_F   1e-7f
#define NCHUNK  256    // row chunks for read_vec partials (8192/NCHUNK=32 rows/chunk)

typedef float f4 __attribute__((ext_vector_type(4)));

__device__ __forceinline__ f4 nt4(const f4* p) { return __builtin_nontemporal_load(p); }
__device__ __forceinline__ float hsum4(f4 v) { return v.x + v.y + v.z + v.w; }

__device__ __forceinline__ float waveReduceSum(float v) {
    #pragma unroll
    for (int off = 32; off > 0; off >>= 1) v += __shfl_xor(v, off, 64);
    return v;
}
__device__ __forceinline__ float waveReduceMax(float v) {
    #pragma unroll
    for (int off = 32; off > 0; off >>= 1) v = fmaxf(v, __shfl_xor(v, off, 64));
    return v;
}

// ---------------------------------------------------------------- K1: all mat-vecs, block-per-row
// CACHING POLICY (R5-R9 A/B measured): nt ONLY on single-use weight streams.
//  - nt W loads: matvec 82 -> <49 us (R6).
//  - ma/mc MUST stay cached: nt reads cost +16 us (R8); L3 reuse K3->K5 is real.
//  - nt newmem store: -2.3 us (R6 vs R8) + protects ma/mc L3 residency.
// NO last-block fusion: R9's per-block __threadfence() serialized the chip (48->446us).
__global__ __launch_bounds__(256) void k_matvec(
    const float* __restrict__ h, const float* __restrict__ x,
    const float* __restrict__ Wq, const float* __restrict__ bq,
    const float* __restrict__ We, const float* __restrict__ be,
    const float* __restrict__ Wch, const float* __restrict__ Wci,
    float* __restrict__ q_out, float* __restrict__ erase_out,
    float* __restrict__ wh_out, float* __restrict__ wx_out)
{
    __shared__ float red[4];
    int tid  = threadIdx.x;
    int lane = tid & 63;
    int wid  = tid >> 6;
    int blk  = blockIdx.x;

    float acc;
    float bias = 0.f;
    float* out;

    if (blk < 6656) {
        const float* W;
        if (blk < 2560)      { int r = blk;        W = Wq  + (size_t)r * 8192; bias = bq[r]; out = q_out + r; }
        else if (blk < 4608) { int r = blk - 2560; W = We  + (size_t)r * 8192; bias = be[r]; out = erase_out + r; }
        else                 { int r = blk - 4608; W = Wch + (size_t)r * 8192; out = wh_out + r; }

        const f4* W4 = (const f4*)W;
        const f4* h4 = (const f4*)h;
        f4 w[8], v[8];
        #pragma unroll
        for (int u = 0; u < 8; ++u) w[u] = nt4(W4 + tid + 256 * u);
        #pragma unroll
        for (int u = 0; u < 8; ++u) v[u] = h4[tid + 256 * u];
        f4 a4 = w[0] * v[0];
        #pragma unroll
        for (int u = 1; u < 8; ++u) a4 += w[u] * v[u];
        acc = hsum4(a4);
    } else {
        int r = blk - 6656;              // 0..2047
        const f4* W4 = (const f4*)(Wci + (size_t)r * 1024);
        const f4* x4 = (const f4*)x;
        f4 w = nt4(W4 + tid);
        f4 v = x4[tid];
        acc = hsum4(w * v);
        out = wx_out + r;
    }

    acc = waveReduceSum(acc);
    if (lane == 0) red[wid] = acc;
    __syncthreads();
    if (tid == 0) *out = red[0] + red[1] + red[2] + red[3] + bias;
}

// ---------------------------------------------------------------- K2: scalars + cdiff
// scal[0]=beta, scal[1]=gamma, scal[2]=q_norm, scal[3]=alpha
__global__ void k_scalars(const float* __restrict__ h, const float* __restrict__ x,
                          const float* __restrict__ us, const float* __restrict__ bs,
                          const float* __restrict__ ul, const float* __restrict__ bl,
                          const float* __restrict__ uca, const float* __restrict__ bca,
                          const float* __restrict__ q, const float* __restrict__ erase,
                          const float* __restrict__ wh, const float* __restrict__ wx,
                          float* __restrict__ scal, float* __restrict__ cdiff)
{
    __shared__ float red[16];
    __shared__ float sh_alpha;
    int tid = threadIdx.x, lane = tid & 63, wid = tid >> 6;

    float s_us = 0.f, s_ul = 0.f, s_a = 0.f, s_q2 = 0.f;
    for (int i = tid; i < 8192; i += 1024) {
        float hv = h[i];
        s_us += us[i] * hv;
        s_ul += ul[i] * hv;
        s_a  += uca[i] * hv;
    }
    { int i = tid; if (i < 1024) s_a += uca[8192 + i] * x[i]; }
    for (int i = tid; i < 2560; i += 1024) { float qv = q[i]; s_q2 += qv * qv; }

    float vals[4] = { s_us, s_ul, s_a, s_q2 };
    float res[4];
    #pragma unroll
    for (int k = 0; k < 4; ++k) {
        float v = waveReduceSum(vals[k]);
        __syncthreads();
        if (lane == 0) red[wid] = v;
        __syncthreads();
        float r = 0.f;
        if (tid == 0) { for (int i = 0; i < 16; ++i) r += red[i]; }
        res[k] = r;
    }

    if (tid == 0) {
        float z = res[0] + bs[0];
        float sp = (z > 20.f) ? z : log1pf(expf(z));
        float beta  = sp + 1.0f;
        float gamma = 1.f / (1.f + expf(-(res[1] + bl[0])));
        float alpha = res[2] + bca[0];
        float qn    = fmaxf(sqrtf(res[3]), EPS_F);
        scal[0] = beta; scal[1] = gamma; scal[2] = qn; scal[3] = alpha;
        sh_alpha = alpha;
    }
    __syncthreads();
    float alpha = sh_alpha;
    for (int j = tid; j < 2048; j += 1024) {
        float cand = fmaxf(wh[j] + alpha * wx[j], 0.f);
        cdiff[j] = cand - erase[j];
    }
}

// ---------------------------------------------------------------- K3: row pass (dots, norms, logits, new_ema)
// Cached reads: allocates ma/mc into L3 so K5 hits (R8 proved this reuse is worth 16us).
__global__ void k_rowpass(const float* __restrict__ ma, const float* __restrict__ mc,
                          const float* __restrict__ q, const float* __restrict__ ema,
                          const float* __restrict__ scal,
                          float* __restrict__ logit, float* __restrict__ newema_out)
{
    int wave = (blockIdx.x * blockDim.x + threadIdx.x) >> 6;
    int lane = threadIdx.x & 63;
    if (wave >= N_LOC) return;
    int row = wave;

    const f4* a4 = (const f4*)(ma + (size_t)row * A_SIZE);
    const f4* c4 = (const f4*)(mc + (size_t)row * C_SIZE);
    const f4* q4 = (const f4*)q;

    f4 dv = {0.f, 0.f, 0.f, 0.f}, sv = {0.f, 0.f, 0.f, 0.f};
    #pragma unroll
    for (int i = lane; i < 128; i += 64) {           // address part: 512 floats
        f4 v = a4[i], qq = q4[i];
        dv += v * qq;
        sv += v * v;
    }
    #pragma unroll
    for (int i = lane; i < 512; i += 64) {           // contents part: 2048 floats
        f4 v = c4[i], qq = q4[128 + i];
        dv += v * qq;
        sv += v * v;
    }
    float dot = hsum4(dv);
    float ssq = hsum4(sv);
    dot = waveReduceSum(dot);
    ssq = waveReduceSum(ssq);
    if (lane == 0) {
        float beta = scal[0], gamma = scal[1], qn = scal[2];
        float mn  = fmaxf(sqrtf(ssq), EPS_F);
        float sim = beta * dot / (mn * qn);
        float e   = ema[row];
        logit[row]      = sim - gamma * e;
        newema_out[row] = 0.1f * e + 0.9f * sim;
    }
}

// ---------------------------------------------------------------- K4: softmax over 8192 logits
__global__ void k_softmax(const float* __restrict__ logit, float* __restrict__ addr_out)
{
    __shared__ float red[16];
    __shared__ float s_max, s_sum;
    int tid = threadIdx.x, lane = tid & 63, wid = tid >> 6;

    float v[8];
    float lmax = -INFINITY;
    #pragma unroll
    for (int k = 0; k < 8; ++k) { v[k] = logit[tid + k * 1024]; lmax = fmaxf(lmax, v[k]); }
    lmax = waveReduceMax(lmax);
    if (lane == 0) red[wid] = lmax;
    __syncthreads();
    if (tid == 0) { float m = red[0]; for (int i = 1; i < 16; ++i) m = fmaxf(m, red[i]); s_max = m; }
    __syncthreads();
    float m = s_max, lsum = 0.f;
    #pragma unroll
    for (int k = 0; k < 8; ++k) { v[k] = expf(v[k] - m); lsum += v[k]; }
    lsum = waveReduceSum(lsum);
    __syncthreads();
    if (lane == 0) red[wid] = lsum;
    __syncthreads();
    if (tid == 0) { float s = 0.f; for (int i = 0; i < 16; ++i) s += red[i]; s_sum = s; }
    __syncthreads();
    float inv = 1.f / s_sum;
    #pragma unroll
    for (int k = 0; k < 8; ++k) addr_out[tid + k * 1024] = v[k] * inv;
}

// ---------------------------------------------------------------- K5: fused column pass (new_mem + read_vec partials)
// float4 per thread (16B/lane, G13), cached ma/mc reads (L3 hits from K3),
// nt stores for newmem (single write; keeps L3 for ma/mc).
// grid (2, NCHUNK), block 320: thread owns one f4-column within a 32-row chunk.
__global__ __launch_bounds__(320) void k_colpass(
    const float* __restrict__ ma, const float* __restrict__ mc,
    const float* __restrict__ addr, const float* __restrict__ cdiff,
    float* __restrict__ newmem_out, float* __restrict__ rvpart)
{
    int c4    = blockIdx.x * 320 + threadIdx.x;   // 0..639 (f4 column)
    int chunk = blockIdx.y;                       // 0..NCHUNK-1
    const int RPC = N_LOC / NCHUNK;               // 32
    int r0 = chunk * RPC, r1 = r0 + RPC;

    f4 acc = {0.f, 0.f, 0.f, 0.f};
    if (c4 < 128) {                               // ma region: 128 f4 per row
        const f4* p = (const f4*)ma + c4;
        for (int r = r0; r < r1; ++r) {
            f4 v = p[(size_t)r * 128];
            float a = addr[r];
            if (r != N_LOC - 1) acc += a * v;
        }
    } else {                                      // mc region: 512 f4 per row
        int cc = c4 - 128;
        f4 cd = ((const f4*)cdiff)[cc];
        const f4* p = (const f4*)mc + cc;
        f4* o = (f4*)newmem_out + cc;
        for (int r = r0; r < r1; ++r) {
            f4 v = p[(size_t)r * 512];
            float a = addr[r];
            if (r != N_LOC - 1) acc += a * v;
            __builtin_nontemporal_store(v + a * cd, o + (size_t)r * 512);
        }
    }
    ((f4*)rvpart)[(size_t)chunk * 640 + c4] = acc;
}

// ---------------------------------------------------------------- K6: reduce read_vec partials (f4)
__global__ void k_rvreduce(const float* __restrict__ rvpart, float* __restrict__ rv_out)
{
    int c4 = blockIdx.x * 256 + threadIdx.x;
    if (c4 >= 640) return;
    const f4* rp = (const f4*)rvpart;
    f4 s = {0.f, 0.f, 0.f, 0.f};
    for (int k = 0; k < NCHUNK; ++k) s += rp[(size_t)k * 640 + c4];
    ((f4*)rv_out)[c4] = s;
}

// ---------------------------------------------------------------- launch
extern "C" void kernel_launch(void* const* d_in, const int* in_sizes, int n_in,
                              void* d_out, int out_size, void* d_ws, size_t ws_size,
                              hipStream_t stream)
{
    const float* h   = (const float*)d_in[0];
    const float* x   = (const float*)d_in[1];
    const float* mc  = (const float*)d_in[2];
    const float* ma  = (const float*)d_in[3];
    const float* ema = (const float*)d_in[4];
    const float* Wq  = (const float*)d_in[5];
    const float* bq  = (const float*)d_in[6];
    const float* us  = (const float*)d_in[7];
    const float* bs  = (const float*)d_in[8];
    const float* ul  = (const float*)d_in[9];
    const float* bl  = (const float*)d_in[10];
    const float* We  = (const float*)d_in[11];
    const float* be  = (const float*)d_in[12];
    const float* Wch = (const float*)d_in[13];
    const float* Wci = (const float*)d_in[14];
    const float* uca = (const float*)d_in[15];
    const float* bca = (const float*)d_in[16];

    float* out = (float*)d_out;
    float* rv_out     = out;                              // 2560
    float* newmem_out = out + D_FULL;                     // 8192*2048
    float* addr_out   = newmem_out + (size_t)N_LOC * C_SIZE; // 8192
    float* newema_out = addr_out + N_LOC;                 // 8192

    float* ws = (float*)d_ws;
    float* w_query = ws;            // 2560
    float* w_erase = ws + 2560;     // 2048
    float* w_wh    = ws + 4608;     // 2048
    float* w_wx    = ws + 6656;     // 2048
    float* w_cdiff = ws + 8704;     // 2048
    float* w_scal  = ws + 10752;    // 8
    float* w_logit = ws + 10760;    // 8192
    float* w_rvp   = ws + 18952;    // NCHUNK*2560

    // K1: all mat-vecs, block-per-row (6656 h-rows + 2048 x-rows), nt W-stream
    k_matvec<<<8704, 256, 0, stream>>>(h, x, Wq, bq, We, be, Wch, Wci,
                                       w_query, w_erase, w_wh, w_wx);
    // K2: scalars + cdiff
    k_scalars<<<1, 1024, 0, stream>>>(h, x, us, bs, ul, bl, uca, bca,
                                      w_query, w_erase, w_wh, w_wx, w_scal, w_cdiff);
    // K3: per-row dot/norm -> logit, new_ema (cached: allocates ma/mc for K5)
    k_rowpass<<<2048, 256, 0, stream>>>(ma, mc, w_query, ema, w_scal, w_logit, newema_out);
    // K4: softmax -> address
    k_softmax<<<1, 1024, 0, stream>>>(w_logit, addr_out);
    // K5: fused new_mem + read_vec partials (f4, cached reads, nt stores)
    dim3 g5(2, NCHUNK);
    k_colpass<<<g5, 320, 0, stream>>>(ma, mc, addr_out, w_cdiff, newmem_out, w_rvp);
    // K6: reduce read_vec partials
    k_rvreduce<<<3, 256, 0, stream>>>(w_rvp, rv_out);
}

// Round 11
// 99.720 us; speedup vs baseline: 5.0267x; 1.0341x over previous
//
#include <hip/hip_runtime.h>
#include <hip/hip_bf16.h>
#include <math.h>

#define N_LOC   8192
#define C_SIZE  2048
#define A_SIZE  512
#define CTRL_IN 1024
#define D_FULL  2560   // A_SIZE + C_SIZE
#define EPS_F   1e-7f
#define NCHUNK  128    // row chunks for read_vec partials (8192/NCHUNK=64 rows/chunk)

typedef float f4 __attribute__((ext_vector_type(4)));

__device__ __forceinline__ f4 nt4(const f4* p) { return __builtin_nontemporal_load(p); }
__device__ __forceinline__ float hsum4(f4 v) { return v.x + v.y + v.z + v.w; }

__device__ __forceinline__ float waveReduceSum(float v) {
    #pragma unroll
    for (int off = 32; off > 0; off >>= 1) v += __shfl_xor(v, off, 64);
    return v;
}
__device__ __forceinline__ float waveReduceMax(float v) {
    #pragma unroll
    for (int off = 32; off > 0; off >>= 1) v = fmaxf(v, __shfl_xor(v, off, 64));
    return v;
}

// ---------------------------------------------------------------- K1: all mat-vecs, block-per-row
// CACHING POLICY (R5-R10 A/B measured): nt ONLY on single-use weight streams.
//  - nt W loads: matvec 82 -> <49 us (R6).
//  - ma/mc cached: nt reads cost +16 us (R8); L3 reuse K3->K5 is real.
//  - newmem store CACHED, colpass scalar (R10: f4+nt-store variant was +4.4 us vs R7).
//  - NO per-block __threadfence / last-block fusion (R9: 48 -> 446 us).
__global__ __launch_bounds__(256) void k_matvec(
    const float* __restrict__ h, const float* __restrict__ x,
    const float* __restrict__ Wq, const float* __restrict__ bq,
    const float* __restrict__ We, const float* __restrict__ be,
    const float* __restrict__ Wch, const float* __restrict__ Wci,
    float* __restrict__ q_out, float* __restrict__ erase_out,
    float* __restrict__ wh_out, float* __restrict__ wx_out)
{
    __shared__ float red[4];
    int tid  = threadIdx.x;
    int lane = tid & 63;
    int wid  = tid >> 6;
    int blk  = blockIdx.x;

    float acc;
    float bias = 0.f;
    float* out;

    if (blk < 6656) {
        const float* W;
        if (blk < 2560)      { int r = blk;        W = Wq  + (size_t)r * 8192; bias = bq[r]; out = q_out + r; }
        else if (blk < 4608) { int r = blk - 2560; W = We  + (size_t)r * 8192; bias = be[r]; out = erase_out + r; }
        else                 { int r = blk - 4608; W = Wch + (size_t)r * 8192; out = wh_out + r; }

        const f4* W4 = (const f4*)W;
        const f4* h4 = (const f4*)h;
        f4 w[8], v[8];
        #pragma unroll
        for (int u = 0; u < 8; ++u) w[u] = nt4(W4 + tid + 256 * u);
        #pragma unroll
        for (int u = 0; u < 8; ++u) v[u] = h4[tid + 256 * u];
        f4 a4 = w[0] * v[0];
        #pragma unroll
        for (int u = 1; u < 8; ++u) a4 += w[u] * v[u];
        acc = hsum4(a4);
    } else {
        int r = blk - 6656;              // 0..2047
        const f4* W4 = (const f4*)(Wci + (size_t)r * 1024);
        const f4* x4 = (const f4*)x;
        f4 w = nt4(W4 + tid);
        f4 v = x4[tid];
        acc = hsum4(w * v);
        out = wx_out + r;
    }

    acc = waveReduceSum(acc);
    if (lane == 0) red[wid] = acc;
    __syncthreads();
    if (tid == 0) *out = red[0] + red[1] + red[2] + red[3] + bias;
}

// ---------------------------------------------------------------- K3': row pass -> raw dot/ssq per row
// No dependency on scalars anymore: epilogue moved into k_fuse. Cached reads
// (allocates ma/mc into L3 so K5 hits).
__global__ void k_rowpass(const float* __restrict__ ma, const float* __restrict__ mc,
                          const float* __restrict__ q,
                          float* __restrict__ dotb, float* __restrict__ ssqb)
{
    int wave = (blockIdx.x * blockDim.x + threadIdx.x) >> 6;
    int lane = threadIdx.x & 63;
    if (wave >= N_LOC) return;
    int row = wave;

    const f4* a4 = (const f4*)(ma + (size_t)row * A_SIZE);
    const f4* c4 = (const f4*)(mc + (size_t)row * C_SIZE);
    const f4* q4 = (const f4*)q;

    f4 dv = {0.f, 0.f, 0.f, 0.f}, sv = {0.f, 0.f, 0.f, 0.f};
    #pragma unroll
    for (int i = lane; i < 128; i += 64) {           // address part: 512 floats
        f4 v = a4[i], qq = q4[i];
        dv += v * qq;
        sv += v * v;
    }
    #pragma unroll
    for (int i = lane; i < 512; i += 64) {           // contents part: 2048 floats
        f4 v = c4[i], qq = q4[128 + i];
        dv += v * qq;
        sv += v * v;
    }
    float dot = waveReduceSum(hsum4(dv));
    float ssq = waveReduceSum(hsum4(sv));
    if (lane == 0) {
        dotb[row] = dot;
        ssqb[row] = ssq;
    }
}

// ---------------------------------------------------------------- K24: fused scalars + sim/logit/new_ema + softmax + cdiff
// Single block, 1024 threads. Replaces R7's k_scalars and k_softmax dispatches;
// logits never touch memory.
__global__ __launch_bounds__(1024) void k_fuse(
    const float* __restrict__ h, const float* __restrict__ x,
    const float* __restrict__ us, const float* __restrict__ bs,
    const float* __restrict__ ul, const float* __restrict__ bl,
    const float* __restrict__ uca, const float* __restrict__ bca,
    const float* __restrict__ q, const float* __restrict__ erase,
    const float* __restrict__ wh, const float* __restrict__ wx,
    const float* __restrict__ dotb, const float* __restrict__ ssqb,
    const float* __restrict__ ema,
    float* __restrict__ addr_out, float* __restrict__ newema_out,
    float* __restrict__ cdiff)
{
    __shared__ float red[16];
    __shared__ float s_beta, s_gamma, s_qn, s_alpha, s_max, s_sum;
    int tid = threadIdx.x, lane = tid & 63, wid = tid >> 6;

    // ---- Phase A: scalar dot products (h-driven + q norm)
    float a_us = 0.f, a_ul = 0.f, a_a = 0.f, a_q2 = 0.f;
    for (int i = tid; i < 8192; i += 1024) {
        float hv = h[i];
        a_us += us[i] * hv;
        a_ul += ul[i] * hv;
        a_a  += uca[i] * hv;
    }
    a_a += uca[8192 + tid] * x[tid];              // 1024 threads cover x exactly
    for (int i = tid; i < 2560; i += 1024) { float qv = q[i]; a_q2 += qv * qv; }

    float vals[4] = { a_us, a_ul, a_a, a_q2 };
    float res[4];
    #pragma unroll
    for (int k = 0; k < 4; ++k) {
        float v = waveReduceSum(vals[k]);
        __syncthreads();
        if (lane == 0) red[wid] = v;
        __syncthreads();
        float r = 0.f;
        if (tid == 0) { for (int i = 0; i < 16; ++i) r += red[i]; }
        res[k] = r;
    }
    if (tid == 0) {
        float z = res[0] + bs[0];
        float sp = (z > 20.f) ? z : log1pf(expf(z));
        s_beta  = sp + 1.0f;
        s_gamma = 1.f / (1.f + expf(-(res[1] + bl[0])));
        s_alpha = res[2] + bca[0];
        s_qn    = fmaxf(sqrtf(res[3]), EPS_F);
    }
    __syncthreads();

    // ---- Phase B: sim/logit/new_ema per row (logits stay in registers)
    float beta = s_beta, gamma = s_gamma, qn = s_qn;
    float v[8];
    float lmax = -INFINITY;
    #pragma unroll
    for (int k = 0; k < 8; ++k) {
        int r = tid + k * 1024;
        float d  = dotb[r];
        float sq = ssqb[r];
        float e  = ema[r];
        float mn  = fmaxf(sqrtf(sq), EPS_F);
        float sim = beta * d / (mn * qn);
        v[k] = sim - gamma * e;
        newema_out[r] = 0.1f * e + 0.9f * sim;
        lmax = fmaxf(lmax, v[k]);
    }

    // ---- Phase C: softmax
    lmax = waveReduceMax(lmax);
    __syncthreads();
    if (lane == 0) red[wid] = lmax;
    __syncthreads();
    if (tid == 0) { float m = red[0]; for (int i = 1; i < 16; ++i) m = fmaxf(m, red[i]); s_max = m; }
    __syncthreads();
    float m = s_max, lsum = 0.f;
    #pragma unroll
    for (int k = 0; k < 8; ++k) { v[k] = expf(v[k] - m); lsum += v[k]; }
    lsum = waveReduceSum(lsum);
    __syncthreads();
    if (lane == 0) red[wid] = lsum;
    __syncthreads();
    if (tid == 0) { float s = 0.f; for (int i = 0; i < 16; ++i) s += red[i]; s_sum = s; }
    __syncthreads();
    float inv = 1.f / s_sum;
    #pragma unroll
    for (int k = 0; k < 8; ++k) addr_out[tid + k * 1024] = v[k] * inv;

    // ---- Phase D: cdiff
    float al = s_alpha;
    for (int j = tid; j < 2048; j += 1024) {
        float cand = fmaxf(wh[j] + al * wx[j], 0.f);
        cdiff[j] = cand - erase[j];
    }
}

// ---------------------------------------------------------------- K5: fused column pass (new_mem + read_vec partials)
// Exact R7 form: scalar cached reads (L3 hits from K3'), cached stores.
__global__ void k_colpass(const float* __restrict__ ma, const float* __restrict__ mc,
                          const float* __restrict__ addr, const float* __restrict__ cdiff,
                          float* __restrict__ newmem_out, float* __restrict__ rvpart)
{
    int c     = blockIdx.x * 256 + threadIdx.x;   // 0..2559
    int chunk = blockIdx.y;                       // 0..NCHUNK-1
    const int RPC = N_LOC / NCHUNK;               // 64
    int r0 = chunk * RPC, r1 = r0 + RPC;

    float acc = 0.f;
    if (c < A_SIZE) {
        const float* p = ma + c;
        for (int r = r0; r < r1; ++r) {
            float val = p[(size_t)r * A_SIZE];
            float a = addr[r];
            if (r != N_LOC - 1) acc += a * val;
        }
    } else {
        int cc = c - A_SIZE;
        float cd = cdiff[cc];
        const float* p = mc + cc;
        float* o = newmem_out + cc;
        for (int r = r0; r < r1; ++r) {
            float val = p[(size_t)r * C_SIZE];
            float a = addr[r];
            if (r != N_LOC - 1) acc += a * val;
            o[(size_t)r * C_SIZE] = val + a * cd;
        }
    }
    rvpart[(size_t)chunk * D_FULL + c] = acc;
}

// ---------------------------------------------------------------- K6: reduce read_vec partials
__global__ void k_rvreduce(const float* __restrict__ rvpart, float* __restrict__ rv_out)
{
    int c = blockIdx.x * 256 + threadIdx.x;
    if (c >= D_FULL) return;
    float s = 0.f;
    for (int k = 0; k < NCHUNK; ++k) s += rvpart[(size_t)k * D_FULL + c];
    rv_out[c] = s;
}

// ---------------------------------------------------------------- launch
extern "C" void kernel_launch(void* const* d_in, const int* in_sizes, int n_in,
                              void* d_out, int out_size, void* d_ws, size_t ws_size,
                              hipStream_t stream)
{
    const float* h   = (const float*)d_in[0];
    const float* x   = (const float*)d_in[1];
    const float* mc  = (const float*)d_in[2];
    const float* ma  = (const float*)d_in[3];
    const float* ema = (const float*)d_in[4];
    const float* Wq  = (const float*)d_in[5];
    const float* bq  = (const float*)d_in[6];
    const float* us  = (const float*)d_in[7];
    const float* bs  = (const float*)d_in[8];
    const float* ul  = (const float*)d_in[9];
    const float* bl  = (const float*)d_in[10];
    const float* We  = (const float*)d_in[11];
    const float* be  = (const float*)d_in[12];
    const float* Wch = (const float*)d_in[13];
    const float* Wci = (const float*)d_in[14];
    const float* uca = (const float*)d_in[15];
    const float* bca = (const float*)d_in[16];

    float* out = (float*)d_out;
    float* rv_out     = out;                              // 2560
    float* newmem_out = out + D_FULL;                     // 8192*2048
    float* addr_out   = newmem_out + (size_t)N_LOC * C_SIZE; // 8192
    float* newema_out = addr_out + N_LOC;                 // 8192

    float* ws = (float*)d_ws;
    float* w_query = ws;            // 2560
    float* w_erase = ws + 2560;     // 2048
    float* w_wh    = ws + 4608;     // 2048
    float* w_wx    = ws + 6656;     // 2048
    float* w_cdiff = ws + 8704;     // 2048
    float* w_dot   = ws + 10752;    // 8192
    float* w_ssq   = ws + 18944;    // 8192
    float* w_rvp   = ws + 27136;    // NCHUNK*2560

    // K1: all mat-vecs, block-per-row (6656 h-rows + 2048 x-rows), nt W-stream
    k_matvec<<<8704, 256, 0, stream>>>(h, x, Wq, bq, We, be, Wch, Wci,
                                       w_query, w_erase, w_wh, w_wx);
    // K3': per-row raw dot/ssq (needs only q from K1; allocates ma/mc into L3)
    k_rowpass<<<2048, 256, 0, stream>>>(ma, mc, w_query, w_dot, w_ssq);
    // K24: fused scalars + logits + softmax + new_ema + cdiff (one block)
    k_fuse<<<1, 1024, 0, stream>>>(h, x, us, bs, ul, bl, uca, bca,
                                   w_query, w_erase, w_wh, w_wx,
                                   w_dot, w_ssq, ema,
                                   addr_out, newema_out, w_cdiff);
    // K5: fused new_mem + read_vec partials (R7 form)
    dim3 g5(D_FULL / 256, NCHUNK);
    k_colpass<<<g5, 256, 0, stream>>>(ma, mc, addr_out, w_cdiff, newmem_out, w_rvp);
    // K6: reduce read_vec partials
    k_rvreduce<<<10, 256, 0, stream>>>(w_rvp, rv_out);
}